// Round 5
// baseline (406.282 us; speedup 1.0000x reference)
//
#include <hip/hip_runtime.h>
#include <hip/hip_bf16.h>

#define NB 2
#define NL 2048
#define NH 12
#define ND 64
#define NEWTON 6
#define WV 8            // waves per block (attn)
#define TPW 16          // key-tiles per wave = 128/WV

typedef __bf16 bf16x8 __attribute__((ext_vector_type(8)));
typedef float f32x4 __attribute__((ext_vector_type(4)));
typedef float f32x2 __attribute__((ext_vector_type(2)));

// DPP row_ror reductions within each 16-lane row.
#define ROR_ADD(v, n)                                                         \
  (v) += __int_as_float(__builtin_amdgcn_update_dpp(                          \
      0, __float_as_int(v), 0x120 + (n), 0xF, 0xF, true))
#define ROR_MAX(v, n)                                                         \
  (v) = fmaxf((v), __int_as_float(__builtin_amdgcn_update_dpp(                \
                  0, __float_as_int(v), 0x120 + (n), 0xF, 0xF, true)))

__device__ __forceinline__ void split_bf16(float f, __bf16& hi, __bf16& lo) {
  __bf16 h = (__bf16)f;
  hi = h;
  lo = (__bf16)(f - (float)h);
}

// ---- prep: block = (b, kt16, head-group of 4) x {K,V}. 1536 blocks, 256 thr,
// 16.6 KB LDS. K-blocks and V-blocks are independent for 2x parallelism.
__global__ __launch_bounds__(256) void prep(
    const float* __restrict__ kg, const float* __restrict__ vg,
    __bf16* __restrict__ kp_hi, __bf16* __restrict__ kp_lo,
    __bf16* __restrict__ vp_hi, __bf16* __restrict__ vp_lo) {
  __shared__ __align__(16) float kv[16][260];  // [key][4 heads x 64 d]
  const int blk = blockIdx.x;
  const int isV = blk >= NB * 128 * 3;
  const int bk = isV ? blk - NB * 128 * 3 : blk;
  const int hg = bk % 3;
  const int kt = (bk / 3) & 127;
  const int b = bk / 384;
  const int t = threadIdx.x;
  const int w = t >> 6;           // wave 0..3 == local head
  const int lane = t & 63;
  const int quad = lane >> 4;
  const int l16 = lane & 15;

  const float* __restrict__ src = isV ? vg : kg;
#pragma unroll
  for (int i = 0; i < 4; ++i) {
    const int f = i * 1024 + t * 4;
    const int key = f >> 8;
    const int rem = f & 255;
    const size_t s =
        (size_t)(b * NL + kt * 16 + key) * (NH * ND) + hg * 256 + rem;
    *(f32x4*)(&kv[key][rem]) = *(const f32x4*)(src + s);
  }
  __syncthreads();

  const int h = hg * 4 + w;

  if (!isV) {
    // ---- K pack ----
    const float* p = &kv[l16][w * 64 + quad * 8];
    f32x4 a0 = *(const f32x4*)(p);
    f32x4 a1 = *(const f32x4*)(p + 4);
    f32x4 a2 = *(const f32x4*)(p + 32);
    f32x4 a3 = *(const f32x4*)(p + 36);
    bf16x8 h0, l0, h1, l1;
#pragma unroll
    for (int j = 0; j < 4; ++j) {
      __bf16 hb, lb;
      split_bf16(a0[j], hb, lb); h0[j] = hb;     l0[j] = lb;
      split_bf16(a1[j], hb, lb); h0[4 + j] = hb; l0[4 + j] = lb;
      split_bf16(a2[j], hb, lb); h1[j] = hb;     l1[j] = lb;
      split_bf16(a3[j], hb, lb); h1[4 + j] = hb; l1[4 + j] = lb;
    }
    const size_t basek =
        ((size_t)((b * NH + h) * 128 + kt) * 2) * 512 + lane * 8;
    *(bf16x8*)(kp_hi + basek) = h0;
    *(bf16x8*)(kp_lo + basek) = l0;
    *(bf16x8*)(kp_hi + basek + 512) = h1;
    *(bf16x8*)(kp_lo + basek + 512) = l1;
  } else {
    // ---- V pack ----
    const int halfsel = (kt >> 3) & 1;
    const int pi = (kt >> 4) * 8 + (kt & 7);
    const int q2 = quad & 1;
    const int nhalf = quad >> 1;
    const int qdst = 2 * halfsel + q2;
#pragma unroll
    for (int nn = 0; nn < 2; ++nn) {
      const int n = nhalf * 2 + nn;
      bf16x8 hv, lv;
#pragma unroll
      for (int j = 0; j < 8; ++j) {
        __bf16 hb, lb;
        split_bf16(kv[q2 * 8 + j][w * 64 + n * 16 + l16], hb, lb);
        hv[j] = hb;
        lv[j] = lb;
      }
      const size_t off =
          ((((size_t)(b * NH + h) * 64 + pi) * 4 + n) * 64 + qdst * 16 + l16) * 8;
      *(bf16x8*)(vp_hi + off) = hv;
      *(bf16x8*)(vp_lo + off) = lv;
    }
  }
}

// ---------------- main fused attention-poly kernel ----------------
__launch_bounds__(512, 6)
__global__ void attn_poly(const float* __restrict__ qg,
                          const __bf16* __restrict__ kp_hi,
                          const __bf16* __restrict__ kp_lo,
                          const __bf16* __restrict__ vp_hi,
                          const __bf16* __restrict__ vp_lo,
                          float* __restrict__ outg) {
  // Half-keyspace weight slab W[16 rows][1024 keys] bf16, XOR-swizzled
  // (byte ^= (row&7)<<4). Phases 4/5 run twice (keys 0-1023, 1024-2047),
  // halving LDS vs a full slab -> 3 blocks/CU. Overlaid with the phase-6
  // partial slab; a barrier separates the last slab read from the first
  // ex write.
  __shared__ __align__(16) union ShMem {
    __bf16 wslab[16][1024];      // 32 KB, phases 4-5 (one key-half)
    float ex[WV][16][68];        // 34.8 KB, phase 6
  } sh;
  __shared__ float redmax[WV][17];
  __shared__ float redn[NEWTON][16][2];   // per-iteration atomic sum buffers

  const int tid = threadIdx.x;
  const int w = tid >> 6;
  const int lane = tid & 63;
  const int quad = lane >> 4;
  const int l16 = lane & 15;

  // XCD-aware swizzle: blocks dispatch round-robin over 8 XCDs (blk&7).
  // Give each XCD 3 complete bh groups (24 bh / 8 XCD) so the concurrent
  // block window on an XCD stays within one bh -> K/V (2MB) L2-resident.
  // Bijective: 3072 = 8 * 384, 384 = 3 * 128.
  const int blk = blockIdx.x;
  const int xcd = blk & 7;
  const int slot = blk >> 3;           // 0..383 within this XCD
  const int bh = xcd * 3 + (slot >> 7);
  const int qt = slot & 127;
  const int h = bh % NH;
  const int b = bh / NH;
  const int qbase = qt * 16;

  // ---- Q fragments: fp32 * 0.125 -> bf16 hi/lo ----
  bf16x8 qhi0, qlo0, qhi1, qlo1;
  {
    const float* qp = qg + ((b * NL + qbase + l16) * NH + h) * ND + quad * 8;
    f32x4 a0 = *(const f32x4*)(qp);
    f32x4 a1 = *(const f32x4*)(qp + 4);
    f32x4 a2 = *(const f32x4*)(qp + 32);
    f32x4 a3 = *(const f32x4*)(qp + 36);
#pragma unroll
    for (int j = 0; j < 4; ++j) {
      __bf16 hb, lb;
      split_bf16(a0[j] * 0.125f, hb, lb); qhi0[j] = hb;     qlo0[j] = lb;
      split_bf16(a1[j] * 0.125f, hb, lb); qhi0[4 + j] = hb; qlo0[4 + j] = lb;
      split_bf16(a2[j] * 0.125f, hb, lb); qhi1[j] = hb;     qlo1[j] = lb;
      split_bf16(a3[j] * 0.125f, hb, lb); qhi1[4 + j] = hb; qlo1[4 + j] = lb;
    }
  }

  // ---- phase 1: S = (Q/8) Kt ; y[t][j] = rows (quad*4+2j, +2j+1), col l16 ----
  // y holds raw scores here; converted to y = negc0 - s after the max phase,
  // then updated in place by the Newton corrections.
  f32x2 y[TPW][2];
  {
    const __bf16* kbh = kp_hi + (size_t)bh * 131072;
    const __bf16* kbl = kp_lo + (size_t)bh * 131072;
#pragma unroll
    for (int t = 0; t < TPW; ++t) {
      const int ktile = w + WV * t;
      const size_t o = (size_t)ktile * 1024 + lane * 8;
      bf16x8 khi0 = *(const bf16x8*)(kbh + o);
      bf16x8 khi1 = *(const bf16x8*)(kbh + o + 512);
      bf16x8 klo0 = *(const bf16x8*)(kbl + o);
      bf16x8 klo1 = *(const bf16x8*)(kbl + o + 512);
      f32x4 acc = {0.f, 0.f, 0.f, 0.f};
      acc = __builtin_amdgcn_mfma_f32_16x16x32_bf16(qhi0, khi0, acc, 0, 0, 0);
      acc = __builtin_amdgcn_mfma_f32_16x16x32_bf16(qhi1, khi1, acc, 0, 0, 0);
      acc = __builtin_amdgcn_mfma_f32_16x16x32_bf16(qhi0, klo0, acc, 0, 0, 0);
      acc = __builtin_amdgcn_mfma_f32_16x16x32_bf16(qhi1, klo1, acc, 0, 0, 0);
      acc = __builtin_amdgcn_mfma_f32_16x16x32_bf16(qlo0, khi0, acc, 0, 0, 0);
      acc = __builtin_amdgcn_mfma_f32_16x16x32_bf16(qlo1, khi1, acc, 0, 0, 0);
      y[t][0] = __builtin_shufflevector(acc, acc, 0, 1);
      y[t][1] = __builtin_shufflevector(acc, acc, 2, 3);
    }
  }

  // ---- phase 2: row max -> negc[j] = -c0 pairs (= max + 1); y := negc - s ----
  {
    f32x2 mx2[2] = {y[0][0], y[0][1]};
#pragma unroll
    for (int t = 1; t < TPW; ++t) {
#pragma unroll
      for (int j = 0; j < 2; ++j) {
        mx2[j].x = fmaxf(mx2[j].x, y[t][j].x);
        mx2[j].y = fmaxf(mx2[j].y, y[t][j].y);
      }
    }
#pragma unroll
    for (int j = 0; j < 2; ++j) {
      ROR_MAX(mx2[j].x, 8); ROR_MAX(mx2[j].x, 4); ROR_MAX(mx2[j].x, 2); ROR_MAX(mx2[j].x, 1);
      ROR_MAX(mx2[j].y, 8); ROR_MAX(mx2[j].y, 4); ROR_MAX(mx2[j].y, 2); ROR_MAX(mx2[j].y, 1);
    }
    if (l16 < 4) {
      float v = (l16 == 0) ? mx2[0].x : (l16 == 1) ? mx2[0].y
              : (l16 == 2) ? mx2[1].x : mx2[1].y;
      redmax[w][quad * 4 + l16] = v;
    }
    // zero the Newton atomic buffers under the same barrier
    if (tid < NEWTON * 16 * 2) ((float*)redn)[tid] = 0.f;
    __syncthreads();
    f32x2 negc[2];
#pragma unroll
    for (int r = 0; r < 4; ++r) {
      float m = redmax[l16 & 7][quad * 4 + r];
      ROR_MAX(m, 4); ROR_MAX(m, 2); ROR_MAX(m, 1);
      ((float*)negc)[r] = m + 1.0f;            // -c0 = max + 1
    }
    // convert scores -> y0 = negc0 - s  (in place)
#pragma unroll
    for (int t = 0; t < TPW; ++t) {
      y[t][0] = negc[0] - y[t][0];
      y[t][1] = negc[1] - y[t][1];
    }
  }

  // ---- phase 3: Newton x6 on c (packed-f32 inner loop; cross-wave via ds_add) ----
  for (int it = 0; it < NEWTON; ++it) {
    f32x2 ps2[2] = {{0.f, 0.f}, {0.f, 0.f}};
    f32x2 psd2[2] = {{0.f, 0.f}, {0.f, 0.f}};
#pragma unroll
    for (int t = 0; t < TPW; ++t) {
#pragma unroll
      for (int j = 0; j < 2; ++j) {
        f32x2 v = y[t][j];                     // y >= 1 along Newton path
        float z = __builtin_amdgcn_rcpf(v.x * v.y);
        f32x2 r1 = z * __builtin_shufflevector(v, v, 1, 0);  // (1/y.x, 1/y.y)
        f32x2 r2;
        asm("v_pk_mul_f32 %0, %1, %1" : "=v"(r2) : "v"(r1));
        asm("v_pk_add_f32 %0, %0, %1" : "+v"(ps2[j]) : "v"(r2));
        asm("v_pk_fma_f32 %0, %1, %2, %0" : "+v"(psd2[j]) : "v"(r2), "v"(r1));
      }
    }
#pragma unroll
    for (int j = 0; j < 2; ++j) {
      ROR_ADD(ps2[j].x, 8);  ROR_ADD(ps2[j].x, 4);  ROR_ADD(ps2[j].x, 2);  ROR_ADD(ps2[j].x, 1);
      ROR_ADD(ps2[j].y, 8);  ROR_ADD(ps2[j].y, 4);  ROR_ADD(ps2[j].y, 2);  ROR_ADD(ps2[j].y, 1);
      ROR_ADD(psd2[j].x, 8); ROR_ADD(psd2[j].x, 4); ROR_ADD(psd2[j].x, 2); ROR_ADD(psd2[j].x, 1);
      ROR_ADD(psd2[j].y, 8); ROR_ADD(psd2[j].y, 4); ROR_ADD(psd2[j].y, 2); ROR_ADD(psd2[j].y, 1);
    }
    if (l16 < 4) {
      float a = (l16 == 0) ? ps2[0].x : (l16 == 1) ? ps2[0].y
              : (l16 == 2) ? ps2[1].x : ps2[1].y;
      float d = (l16 == 0) ? psd2[0].x : (l16 == 1) ? psd2[0].y
              : (l16 == 2) ? psd2[1].x : psd2[1].y;
      atomicAdd(&redn[it][quad * 4 + l16][0], a);
      atomicAdd(&redn[it][quad * 4 + l16][1], d);
    }
    __syncthreads();
    f32x2 dd[2];
#pragma unroll
    for (int r = 0; r < 4; ++r) {
      const f32x2 v = *(const f32x2*)(&redn[it][quad * 4 + r][0]);
      ((float*)dd)[r] =
          (v.x - 1.0f) * __builtin_amdgcn_rcpf(2.0f * v.y + 1e-8f);
    }
#pragma unroll
    for (int t = 0; t < TPW; ++t) {
      y[t][0] += dd[0];
      y[t][1] += dd[1];
    }
  }

  // ---- phases 4+5, two key-halves: materialize half the weights into the
  // 32KB swizzled slab, then consume it with V-MFMAs; repeat for the other
  // half. Tiles t = hh*8 .. hh*8+7 cover keys [hh*1024, hh*1024+1024).
  f32x4 oacc[4];
#pragma unroll
  for (int n = 0; n < 4; ++n) oacc[n] = (f32x4){0.f, 0.f, 0.f, 0.f};
  const __bf16* vpbh = vp_hi + (size_t)bh * 131072;
  const __bf16* vpbl = vp_lo + (size_t)bh * 131072;
  char* slab = (char*)&sh.wslab[0][0];

#pragma unroll
  for (int hh = 0; hh < 2; ++hh) {
    if (hh) __syncthreads();   // half-A reads complete before overwrite

    // ---- phase 4 (half): weights for tiles hh*8 .. hh*8+7 ----
#pragma unroll
    for (int tt = 0; tt < 8; ++tt) {
      const int t = hh * 8 + tt;
      f32x2 a = y[t][0];
      f32x2 bb = y[t][1];
      float za = __builtin_amdgcn_rcpf(a.x * a.y);
      float zb = __builtin_amdgcn_rcpf(bb.x * bb.y);
      f32x2 ra = za * __builtin_shufflevector(a, a, 1, 0);
      f32x2 rb = zb * __builtin_shufflevector(bb, bb, 1, 0);
      f32x2 wa = ra * ra;
      f32x2 wb = rb * rb;
      const int c2 = ((w + WV * t) * 16 + l16) * 2 - hh * 2048;  // local col byte
#pragma unroll
      for (int j = 0; j < 4; ++j) {
        const int r = quad * 4 + j;
        const float wv = (j == 0) ? wa.x : (j == 1) ? wa.y
                       : (j == 2) ? wb.x : wb.y;
        *(__bf16*)(slab + r * 2048 + (c2 ^ ((r & 7) << 4))) = (__bf16)wv;
      }
    }
    __syncthreads();

    // ---- phase 5 (half): p = hh*4 .. hh*4+3 ----
#pragma unroll
    for (int pp = 0; pp < 4; ++pp) {
      const int p = hh * 4 + pp;
      const size_t vo = ((size_t)(p * 8 + w) * 4) * 512 + lane * 8;
      bf16x8 bhv0 = *(const bf16x8*)(vpbh + vo);
      bf16x8 bhv1 = *(const bf16x8*)(vpbh + vo + 512);
      bf16x8 bhv2 = *(const bf16x8*)(vpbh + vo + 1024);
      bf16x8 bhv3 = *(const bf16x8*)(vpbh + vo + 1536);
      bf16x8 blv0 = *(const bf16x8*)(vpbl + vo);
      bf16x8 blv1 = *(const bf16x8*)(vpbl + vo + 512);
      bf16x8 blv2 = *(const bf16x8*)(vpbl + vo + 1024);
      bf16x8 blv3 = *(const bf16x8*)(vpbl + vo + 1536);

      // A-fragment keys must match the V-pack's k ordering:
      //   k = quad*8 + j  ->  key = (16p + 8*(quad>>1) + w)*16 + (quad&1)*8 + j
      // (quads 0-1: kt = 16p+w; quads 2-3: kt = 16p+8+w), row = l16.
      const int c2 =
          ((16 * p + 8 * (quad >> 1) + w) * 16 + (quad & 1) * 8) * 2 - hh * 2048;
      bf16x8 aw =
          *(const bf16x8*)(slab + l16 * 2048 + (c2 ^ ((l16 & 7) << 4)));

      oacc[0] = __builtin_amdgcn_mfma_f32_16x16x32_bf16(aw, bhv0, oacc[0], 0, 0, 0);
      oacc[1] = __builtin_amdgcn_mfma_f32_16x16x32_bf16(aw, bhv1, oacc[1], 0, 0, 0);
      oacc[2] = __builtin_amdgcn_mfma_f32_16x16x32_bf16(aw, bhv2, oacc[2], 0, 0, 0);
      oacc[3] = __builtin_amdgcn_mfma_f32_16x16x32_bf16(aw, bhv3, oacc[3], 0, 0, 0);
      oacc[0] = __builtin_amdgcn_mfma_f32_16x16x32_bf16(aw, blv0, oacc[0], 0, 0, 0);
      oacc[1] = __builtin_amdgcn_mfma_f32_16x16x32_bf16(aw, blv1, oacc[1], 0, 0, 0);
      oacc[2] = __builtin_amdgcn_mfma_f32_16x16x32_bf16(aw, blv2, oacc[2], 0, 0, 0);
      oacc[3] = __builtin_amdgcn_mfma_f32_16x16x32_bf16(aw, blv3, oacc[3], 0, 0, 0);
    }
  }

  // ---- phase 6: reduce partials across waves, write global ----
  __syncthreads();   // all slab reads complete before overlaying ex
#pragma unroll
  for (int n = 0; n < 4; ++n)
#pragma unroll
    for (int r = 0; r < 4; ++r)
      sh.ex[w][quad * 4 + r][n * 16 + l16] = oacc[n][r];
  __syncthreads();
  {
    const int row = 2 * w + (lane >> 5);
    const int d = lane & 31;
    float v0 = 0.f, v1 = 0.f;
#pragma unroll
    for (int i = 0; i < WV; ++i) {
      v0 += sh.ex[i][row][d];
      v1 += sh.ex[i][row][d + 32];
    }
    const int off = ((b * NL + qbase + row) * NH + h) * ND + d;
    outg[off] = v0;
    outg[off + 32] = v1;
  }
}

extern "C" void kernel_launch(void* const* d_in, const int* in_sizes, int n_in,
                              void* d_out, int out_size, void* d_ws, size_t ws_size,
                              hipStream_t stream) {
  const float* q = (const float*)d_in[0];
  const float* k = (const float*)d_in[1];
  const float* v = (const float*)d_in[2];

  const size_t plane = (size_t)NB * NH * ND * NL;  // 3.15M elems, 6.29MB/plane
  __bf16* kp_hi = (__bf16*)d_ws;
  __bf16* kp_lo = kp_hi + plane;
  __bf16* vp_hi = kp_lo + plane;
  __bf16* vp_lo = vp_hi + plane;

  prep<<<NB * 128 * 3 * 2, 256, 0, stream>>>(k, v, kp_hi, kp_lo, vp_hi, vp_lo);

  attn_poly<<<NB * NH * (NL / 16), 512, 0, stream>>>(
      q, kp_hi, kp_lo, vp_hi, vp_lo, (float*)d_out);
}

// Round 6
// 259.602 us; speedup vs baseline: 1.5650x; 1.5650x over previous
//
#include <hip/hip_runtime.h>
#include <hip/hip_bf16.h>

#define NB 2
#define NL 2048
#define NH 12
#define ND 64
#define NEWTON 6
#define WV 8            // waves per block (attn)
#define TPW 16          // key-tiles per wave = 128/WV

typedef __bf16 bf16x8 __attribute__((ext_vector_type(8)));
typedef float f32x4 __attribute__((ext_vector_type(4)));
typedef float f32x2 __attribute__((ext_vector_type(2)));

// DPP row_ror reductions within each 16-lane row.
#define ROR_ADD(v, n)                                                         \
  (v) += __int_as_float(__builtin_amdgcn_update_dpp(                          \
      0, __float_as_int(v), 0x120 + (n), 0xF, 0xF, true))
#define ROR_MAX(v, n)                                                         \
  (v) = fmaxf((v), __int_as_float(__builtin_amdgcn_update_dpp(                \
                  0, __float_as_int(v), 0x120 + (n), 0xF, 0xF, true)))

__device__ __forceinline__ void split_bf16(float f, __bf16& hi, __bf16& lo) {
  __bf16 h = (__bf16)f;
  hi = h;
  lo = (__bf16)(f - (float)h);
}

// ---- prep: block = (b, kt16, head-group of 4) x {K,V}. 1536 blocks, 256 thr,
// 16.6 KB LDS. K-blocks and V-blocks are independent for 2x parallelism.
__global__ __launch_bounds__(256) void prep(
    const float* __restrict__ kg, const float* __restrict__ vg,
    __bf16* __restrict__ kp_hi, __bf16* __restrict__ kp_lo,
    __bf16* __restrict__ vp_hi, __bf16* __restrict__ vp_lo) {
  __shared__ __align__(16) float kv[16][260];  // [key][4 heads x 64 d]
  const int blk = blockIdx.x;
  const int isV = blk >= NB * 128 * 3;
  const int bk = isV ? blk - NB * 128 * 3 : blk;
  const int hg = bk % 3;
  const int kt = (bk / 3) & 127;
  const int b = bk / 384;
  const int t = threadIdx.x;
  const int w = t >> 6;           // wave 0..3 == local head
  const int lane = t & 63;
  const int quad = lane >> 4;
  const int l16 = lane & 15;

  const float* __restrict__ src = isV ? vg : kg;
#pragma unroll
  for (int i = 0; i < 4; ++i) {
    const int f = i * 1024 + t * 4;
    const int key = f >> 8;
    const int rem = f & 255;
    const size_t s =
        (size_t)(b * NL + kt * 16 + key) * (NH * ND) + hg * 256 + rem;
    *(f32x4*)(&kv[key][rem]) = *(const f32x4*)(src + s);
  }
  __syncthreads();

  const int h = hg * 4 + w;

  if (!isV) {
    // ---- K pack ----
    const float* p = &kv[l16][w * 64 + quad * 8];
    f32x4 a0 = *(const f32x4*)(p);
    f32x4 a1 = *(const f32x4*)(p + 4);
    f32x4 a2 = *(const f32x4*)(p + 32);
    f32x4 a3 = *(const f32x4*)(p + 36);
    bf16x8 h0, l0, h1, l1;
#pragma unroll
    for (int j = 0; j < 4; ++j) {
      __bf16 hb, lb;
      split_bf16(a0[j], hb, lb); h0[j] = hb;     l0[j] = lb;
      split_bf16(a1[j], hb, lb); h0[4 + j] = hb; l0[4 + j] = lb;
      split_bf16(a2[j], hb, lb); h1[j] = hb;     l1[j] = lb;
      split_bf16(a3[j], hb, lb); h1[4 + j] = hb; l1[4 + j] = lb;
    }
    const size_t basek =
        ((size_t)((b * NH + h) * 128 + kt) * 2) * 512 + lane * 8;
    *(bf16x8*)(kp_hi + basek) = h0;
    *(bf16x8*)(kp_lo + basek) = l0;
    *(bf16x8*)(kp_hi + basek + 512) = h1;
    *(bf16x8*)(kp_lo + basek + 512) = l1;
  } else {
    // ---- V pack ----
    const int halfsel = (kt >> 3) & 1;
    const int pi = (kt >> 4) * 8 + (kt & 7);
    const int q2 = quad & 1;
    const int nhalf = quad >> 1;
    const int qdst = 2 * halfsel + q2;
#pragma unroll
    for (int nn = 0; nn < 2; ++nn) {
      const int n = nhalf * 2 + nn;
      bf16x8 hv, lv;
#pragma unroll
      for (int j = 0; j < 8; ++j) {
        __bf16 hb, lb;
        split_bf16(kv[q2 * 8 + j][w * 64 + n * 16 + l16], hb, lb);
        hv[j] = hb;
        lv[j] = lb;
      }
      const size_t off =
          ((((size_t)(b * NH + h) * 64 + pi) * 4 + n) * 64 + qdst * 16 + l16) * 8;
      *(bf16x8*)(vp_hi + off) = hv;
      *(bf16x8*)(vp_lo + off) = lv;
    }
  }
}

// ---------------- main fused attention-poly kernel ----------------
__launch_bounds__(512, 4)
__global__ void attn_poly(const float* __restrict__ qg,
                          const __bf16* __restrict__ kp_hi,
                          const __bf16* __restrict__ kp_lo,
                          const __bf16* __restrict__ vp_hi,
                          const __bf16* __restrict__ vp_lo,
                          float* __restrict__ outg) {
  // Half-keyspace weight slab W[16 rows][1024 keys] bf16, XOR-swizzled
  // (byte ^= (row&7)<<4). Phases 4/5 run twice (keys 0-1023, 1024-2047),
  // halving LDS vs a full slab. 35.5 KB total LDS + VGPR<=64 allows
  // 4 blocks/CU (launch_bounds(512,4): allocator targets <=128 VGPR but
  // actual usage ~56; residency is computed from actual usage).
  // NOTE: (512,6) forces VGPR<=85 -> spills y[] -> 594MB scratch traffic
  // (round-5 regression). Do not raise the min-waves bound.
  __shared__ __align__(16) union ShMem {
    __bf16 wslab[16][1024];      // 32 KB, phases 4-5 (one key-half)
    float ex[WV][16][68];        // 34.8 KB, phase 6
  } sh;
  __shared__ float redmax[WV][17];
  __shared__ float redn[NEWTON][16][2];   // per-iteration atomic sum buffers

  const int tid = threadIdx.x;
  const int w = tid >> 6;
  const int lane = tid & 63;
  const int quad = lane >> 4;
  const int l16 = lane & 15;

  // XCD-aware swizzle: blocks dispatch round-robin over 8 XCDs (blk&7).
  // Give each XCD 3 complete bh groups (24 bh / 8 XCD) so the concurrent
  // block window on an XCD stays within one bh -> K/V (2MB) L2-resident.
  // Bijective: 3072 = 8 * 384, 384 = 3 * 128.
  const int blk = blockIdx.x;
  const int xcd = blk & 7;
  const int slot = blk >> 3;           // 0..383 within this XCD
  const int bh = xcd * 3 + (slot >> 7);
  const int qt = slot & 127;
  const int h = bh % NH;
  const int b = bh / NH;
  const int qbase = qt * 16;

  // ---- Q fragments: fp32 * 0.125 -> bf16 hi/lo ----
  bf16x8 qhi0, qlo0, qhi1, qlo1;
  {
    const float* qp = qg + ((b * NL + qbase + l16) * NH + h) * ND + quad * 8;
    f32x4 a0 = *(const f32x4*)(qp);
    f32x4 a1 = *(const f32x4*)(qp + 4);
    f32x4 a2 = *(const f32x4*)(qp + 32);
    f32x4 a3 = *(const f32x4*)(qp + 36);
#pragma unroll
    for (int j = 0; j < 4; ++j) {
      __bf16 hb, lb;
      split_bf16(a0[j] * 0.125f, hb, lb); qhi0[j] = hb;     qlo0[j] = lb;
      split_bf16(a1[j] * 0.125f, hb, lb); qhi0[4 + j] = hb; qlo0[4 + j] = lb;
      split_bf16(a2[j] * 0.125f, hb, lb); qhi1[j] = hb;     qlo1[j] = lb;
      split_bf16(a3[j] * 0.125f, hb, lb); qhi1[4 + j] = hb; qlo1[4 + j] = lb;
    }
  }

  // ---- phase 1: S = (Q/8) Kt ; y[t][j] = rows (quad*4+2j, +2j+1), col l16 ----
  // y holds raw scores here; converted to y = negc0 - s after the max phase,
  // then updated in place by the Newton corrections.
  f32x2 y[TPW][2];
  {
    const __bf16* kbh = kp_hi + (size_t)bh * 131072;
    const __bf16* kbl = kp_lo + (size_t)bh * 131072;
#pragma unroll
    for (int t = 0; t < TPW; ++t) {
      const int ktile = w + WV * t;
      const size_t o = (size_t)ktile * 1024 + lane * 8;
      bf16x8 khi0 = *(const bf16x8*)(kbh + o);
      bf16x8 khi1 = *(const bf16x8*)(kbh + o + 512);
      bf16x8 klo0 = *(const bf16x8*)(kbl + o);
      bf16x8 klo1 = *(const bf16x8*)(kbl + o + 512);
      f32x4 acc = {0.f, 0.f, 0.f, 0.f};
      acc = __builtin_amdgcn_mfma_f32_16x16x32_bf16(qhi0, khi0, acc, 0, 0, 0);
      acc = __builtin_amdgcn_mfma_f32_16x16x32_bf16(qhi1, khi1, acc, 0, 0, 0);
      acc = __builtin_amdgcn_mfma_f32_16x16x32_bf16(qhi0, klo0, acc, 0, 0, 0);
      acc = __builtin_amdgcn_mfma_f32_16x16x32_bf16(qhi1, klo1, acc, 0, 0, 0);
      acc = __builtin_amdgcn_mfma_f32_16x16x32_bf16(qlo0, khi0, acc, 0, 0, 0);
      acc = __builtin_amdgcn_mfma_f32_16x16x32_bf16(qlo1, khi1, acc, 0, 0, 0);
      y[t][0] = __builtin_shufflevector(acc, acc, 0, 1);
      y[t][1] = __builtin_shufflevector(acc, acc, 2, 3);
    }
  }

  // ---- phase 2: row max -> negc[j] = -c0 pairs (= max + 1); y := negc - s ----
  {
    f32x2 mx2[2] = {y[0][0], y[0][1]};
#pragma unroll
    for (int t = 1; t < TPW; ++t) {
#pragma unroll
      for (int j = 0; j < 2; ++j) {
        mx2[j].x = fmaxf(mx2[j].x, y[t][j].x);
        mx2[j].y = fmaxf(mx2[j].y, y[t][j].y);
      }
    }
#pragma unroll
    for (int j = 0; j < 2; ++j) {
      ROR_MAX(mx2[j].x, 8); ROR_MAX(mx2[j].x, 4); ROR_MAX(mx2[j].x, 2); ROR_MAX(mx2[j].x, 1);
      ROR_MAX(mx2[j].y, 8); ROR_MAX(mx2[j].y, 4); ROR_MAX(mx2[j].y, 2); ROR_MAX(mx2[j].y, 1);
    }
    if (l16 < 4) {
      float v = (l16 == 0) ? mx2[0].x : (l16 == 1) ? mx2[0].y
              : (l16 == 2) ? mx2[1].x : mx2[1].y;
      redmax[w][quad * 4 + l16] = v;
    }
    // zero the Newton atomic buffers under the same barrier
    if (tid < NEWTON * 16 * 2) ((float*)redn)[tid] = 0.f;
    __syncthreads();
    f32x2 negc[2];
#pragma unroll
    for (int r = 0; r < 4; ++r) {
      float m = redmax[l16 & 7][quad * 4 + r];
      ROR_MAX(m, 4); ROR_MAX(m, 2); ROR_MAX(m, 1);
      ((float*)negc)[r] = m + 1.0f;            // -c0 = max + 1
    }
    // convert scores -> y0 = negc0 - s  (in place)
#pragma unroll
    for (int t = 0; t < TPW; ++t) {
      y[t][0] = negc[0] - y[t][0];
      y[t][1] = negc[1] - y[t][1];
    }
  }

  // ---- phase 3: Newton x6 on c (packed-f32 inner loop; cross-wave via ds_add) ----
  for (int it = 0; it < NEWTON; ++it) {
    f32x2 ps2[2] = {{0.f, 0.f}, {0.f, 0.f}};
    f32x2 psd2[2] = {{0.f, 0.f}, {0.f, 0.f}};
#pragma unroll
    for (int t = 0; t < TPW; ++t) {
#pragma unroll
      for (int j = 0; j < 2; ++j) {
        f32x2 v = y[t][j];                     // y >= 1 along Newton path
        float z = __builtin_amdgcn_rcpf(v.x * v.y);
        f32x2 r1 = z * __builtin_shufflevector(v, v, 1, 0);  // (1/y.x, 1/y.y)
        f32x2 r2;
        asm("v_pk_mul_f32 %0, %1, %1" : "=v"(r2) : "v"(r1));
        asm("v_pk_add_f32 %0, %0, %1" : "+v"(ps2[j]) : "v"(r2));
        asm("v_pk_fma_f32 %0, %1, %2, %0" : "+v"(psd2[j]) : "v"(r2), "v"(r1));
      }
    }
#pragma unroll
    for (int j = 0; j < 2; ++j) {
      ROR_ADD(ps2[j].x, 8);  ROR_ADD(ps2[j].x, 4);  ROR_ADD(ps2[j].x, 2);  ROR_ADD(ps2[j].x, 1);
      ROR_ADD(ps2[j].y, 8);  ROR_ADD(ps2[j].y, 4);  ROR_ADD(ps2[j].y, 2);  ROR_ADD(ps2[j].y, 1);
      ROR_ADD(psd2[j].x, 8); ROR_ADD(psd2[j].x, 4); ROR_ADD(psd2[j].x, 2); ROR_ADD(psd2[j].x, 1);
      ROR_ADD(psd2[j].y, 8); ROR_ADD(psd2[j].y, 4); ROR_ADD(psd2[j].y, 2); ROR_ADD(psd2[j].y, 1);
    }
    if (l16 < 4) {
      float a = (l16 == 0) ? ps2[0].x : (l16 == 1) ? ps2[0].y
              : (l16 == 2) ? ps2[1].x : ps2[1].y;
      float d = (l16 == 0) ? psd2[0].x : (l16 == 1) ? psd2[0].y
              : (l16 == 2) ? psd2[1].x : psd2[1].y;
      atomicAdd(&redn[it][quad * 4 + l16][0], a);
      atomicAdd(&redn[it][quad * 4 + l16][1], d);
    }
    __syncthreads();
    f32x2 dd[2];
#pragma unroll
    for (int r = 0; r < 4; ++r) {
      const f32x2 v = *(const f32x2*)(&redn[it][quad * 4 + r][0]);
      ((float*)dd)[r] =
          (v.x - 1.0f) * __builtin_amdgcn_rcpf(2.0f * v.y + 1e-8f);
    }
#pragma unroll
    for (int t = 0; t < TPW; ++t) {
      y[t][0] += dd[0];
      y[t][1] += dd[1];
    }
  }

  // ---- phases 4+5, two key-halves: materialize half the weights into the
  // 32KB swizzled slab, then consume it with V-MFMAs; repeat for the other
  // half. Tiles t = hh*8 .. hh*8+7 cover keys [hh*1024, hh*1024+1024).
  f32x4 oacc[4];
#pragma unroll
  for (int n = 0; n < 4; ++n) oacc[n] = (f32x4){0.f, 0.f, 0.f, 0.f};
  const __bf16* vpbh = vp_hi + (size_t)bh * 131072;
  const __bf16* vpbl = vp_lo + (size_t)bh * 131072;
  char* slab = (char*)&sh.wslab[0][0];

#pragma unroll
  for (int hh = 0; hh < 2; ++hh) {
    if (hh) __syncthreads();   // half-A reads complete before overwrite

    // ---- phase 4 (half): weights for tiles hh*8 .. hh*8+7 ----
#pragma unroll
    for (int tt = 0; tt < 8; ++tt) {
      const int t = hh * 8 + tt;
      f32x2 a = y[t][0];
      f32x2 bb = y[t][1];
      float za = __builtin_amdgcn_rcpf(a.x * a.y);
      float zb = __builtin_amdgcn_rcpf(bb.x * bb.y);
      f32x2 ra = za * __builtin_shufflevector(a, a, 1, 0);
      f32x2 rb = zb * __builtin_shufflevector(bb, bb, 1, 0);
      f32x2 wa = ra * ra;
      f32x2 wb = rb * rb;
      const int c2 = ((w + WV * t) * 16 + l16) * 2 - hh * 2048;  // local col byte
#pragma unroll
      for (int j = 0; j < 4; ++j) {
        const int r = quad * 4 + j;
        const float wv = (j == 0) ? wa.x : (j == 1) ? wa.y
                       : (j == 2) ? wb.x : wb.y;
        *(__bf16*)(slab + r * 2048 + (c2 ^ ((r & 7) << 4))) = (__bf16)wv;
      }
    }
    __syncthreads();

    // ---- phase 5 (half): p = hh*4 .. hh*4+3 ----
#pragma unroll
    for (int pp = 0; pp < 4; ++pp) {
      const int p = hh * 4 + pp;
      const size_t vo = ((size_t)(p * 8 + w) * 4) * 512 + lane * 8;
      bf16x8 bhv0 = *(const bf16x8*)(vpbh + vo);
      bf16x8 bhv1 = *(const bf16x8*)(vpbh + vo + 512);
      bf16x8 bhv2 = *(const bf16x8*)(vpbh + vo + 1024);
      bf16x8 bhv3 = *(const bf16x8*)(vpbh + vo + 1536);
      bf16x8 blv0 = *(const bf16x8*)(vpbl + vo);
      bf16x8 blv1 = *(const bf16x8*)(vpbl + vo + 512);
      bf16x8 blv2 = *(const bf16x8*)(vpbl + vo + 1024);
      bf16x8 blv3 = *(const bf16x8*)(vpbl + vo + 1536);

      // A-fragment keys must match the V-pack's k ordering:
      //   k = quad*8 + j  ->  key = (16p + 8*(quad>>1) + w)*16 + (quad&1)*8 + j
      // (quads 0-1: kt = 16p+w; quads 2-3: kt = 16p+8+w), row = l16.
      const int c2 =
          ((16 * p + 8 * (quad >> 1) + w) * 16 + (quad & 1) * 8) * 2 - hh * 2048;
      bf16x8 aw =
          *(const bf16x8*)(slab + l16 * 2048 + (c2 ^ ((l16 & 7) << 4)));

      oacc[0] = __builtin_amdgcn_mfma_f32_16x16x32_bf16(aw, bhv0, oacc[0], 0, 0, 0);
      oacc[1] = __builtin_amdgcn_mfma_f32_16x16x32_bf16(aw, bhv1, oacc[1], 0, 0, 0);
      oacc[2] = __builtin_amdgcn_mfma_f32_16x16x32_bf16(aw, bhv2, oacc[2], 0, 0, 0);
      oacc[3] = __builtin_amdgcn_mfma_f32_16x16x32_bf16(aw, bhv3, oacc[3], 0, 0, 0);
      oacc[0] = __builtin_amdgcn_mfma_f32_16x16x32_bf16(aw, blv0, oacc[0], 0, 0, 0);
      oacc[1] = __builtin_amdgcn_mfma_f32_16x16x32_bf16(aw, blv1, oacc[1], 0, 0, 0);
      oacc[2] = __builtin_amdgcn_mfma_f32_16x16x32_bf16(aw, blv2, oacc[2], 0, 0, 0);
      oacc[3] = __builtin_amdgcn_mfma_f32_16x16x32_bf16(aw, blv3, oacc[3], 0, 0, 0);
    }
  }

  // ---- phase 6: reduce partials across waves, write global ----
  __syncthreads();   // all slab reads complete before overlaying ex
#pragma unroll
  for (int n = 0; n < 4; ++n)
#pragma unroll
    for (int r = 0; r < 4; ++r)
      sh.ex[w][quad * 4 + r][n * 16 + l16] = oacc[n][r];
  __syncthreads();
  {
    const int row = 2 * w + (lane >> 5);
    const int d = lane & 31;
    float v0 = 0.f, v1 = 0.f;
#pragma unroll
    for (int i = 0; i < WV; ++i) {
      v0 += sh.ex[i][row][d];
      v1 += sh.ex[i][row][d + 32];
    }
    const int off = ((b * NL + qbase + row) * NH + h) * ND + d;
    outg[off] = v0;
    outg[off + 32] = v1;
  }
}

extern "C" void kernel_launch(void* const* d_in, const int* in_sizes, int n_in,
                              void* d_out, int out_size, void* d_ws, size_t ws_size,
                              hipStream_t stream) {
  const float* q = (const float*)d_in[0];
  const float* k = (const float*)d_in[1];
  const float* v = (const float*)d_in[2];

  const size_t plane = (size_t)NB * NH * ND * NL;  // 3.15M elems, 6.29MB/plane
  __bf16* kp_hi = (__bf16*)d_ws;
  __bf16* kp_lo = kp_hi + plane;
  __bf16* vp_hi = kp_lo + plane;
  __bf16* vp_lo = vp_hi + plane;

  prep<<<NB * 128 * 3 * 2, 256, 0, stream>>>(k, v, kp_hi, kp_lo, vp_hi, vp_lo);

  attn_poly<<<NB * NH * (NL / 16), 512, 0, stream>>>(
      q, kp_hi, kp_lo, vp_hi, vp_lo, (float*)d_out);
}